// Round 7
// baseline (1323.045 us; speedup 1.0000x reference)
//
#include <hip/hip_runtime.h>

#define NROWS 8192
#define DIM   1024
#define K3    3072
#define NLAYERS 4

typedef unsigned short u16;
typedef __attribute__((ext_vector_type(8))) __bf16 bf16x8;
typedef __attribute__((ext_vector_type(4))) float  f32x4;

__device__ __forceinline__ u16 f2bf(float f) {
  unsigned u = __builtin_bit_cast(unsigned, f);
  u += 0x7FFFu + ((u >> 16) & 1u);   // round-to-nearest-even to bf16
  return (u16)(u >> 16);
}
__device__ __forceinline__ float bf2f(u16 h) {
  unsigned u = ((unsigned)h) << 16;
  return __builtin_bit_cast(float, u);
}

__device__ __forceinline__ void gload16(const void* g, void* l) {
  __builtin_amdgcn_global_load_lds((__attribute__((address_space(1))) void*)g,
                                   (__attribute__((address_space(3))) void*)l,
                                   16, 0, 0);
}

// ---------------------------------------------------------------------------
// W [L][3072][1024] f32  ->  WT_hi/lo [L][1024][3072] bf16 (transposed, split)
// ---------------------------------------------------------------------------
__global__ void k_prep_w(const float* __restrict__ Ws,
                         u16* __restrict__ WThi, u16* __restrict__ WTlo) {
  __shared__ float tile[32][33];
  const int L  = blockIdx.z;
  const int k0 = blockIdx.x * 32;
  const int n0 = blockIdx.y * 32;
  const float* W = Ws + (size_t)L * K3 * DIM;
  u16* hi = WThi + (size_t)L * DIM * K3;
  u16* lo = WTlo + (size_t)L * DIM * K3;
  const int tx = threadIdx.x, ty = threadIdx.y;   // 32 x 8
#pragma unroll
  for (int r = 0; r < 4; ++r)
    tile[ty + r*8][tx] = W[(size_t)(k0 + ty + r*8) * DIM + n0 + tx];
  __syncthreads();
#pragma unroll
  for (int r = 0; r < 4; ++r) {
    const int n = n0 + ty + r*8, k = k0 + tx;
    const float v = tile[tx][ty + r*8];
    const u16 h = f2bf(v);
    hi[(size_t)n * K3 + k] = h;
    lo[(size_t)n * K3 + k] = f2bf(v - bf2f(h));
  }
}

__global__ void k_oob(const float* __restrict__ oob, u16* __restrict__ hi,
                      u16* __restrict__ lo) {
  const int i = blockIdx.x * 256 + threadIdx.x;
  if (i < DIM) {
    const float v = oob[i];
    const u16 h = f2bf(v);
    hi[i] = h;
    lo[i] = f2bf(v - bf2f(h));
  }
}

// X f32 [8192][1024] -> X_hi/lo bf16 (original input only; later layers write
// their activations directly as split pairs in the GEMM epilogue)
__global__ void k_split(const float* __restrict__ X, u16* __restrict__ hi,
                        u16* __restrict__ lo) {
  const int i = blockIdx.x * 256 + threadIdx.x;  // float4 index
  const float4 v = reinterpret_cast<const float4*>(X)[i];
  const u16 h0 = f2bf(v.x), h1 = f2bf(v.y), h2 = f2bf(v.z), h3 = f2bf(v.w);
  ushort4 H; H.x = h0; H.y = h1; H.z = h2; H.w = h3;
  ushort4 L; L.x = f2bf(v.x - bf2f(h0)); L.y = f2bf(v.y - bf2f(h1));
  L.z = f2bf(v.z - bf2f(h2)); L.w = f2bf(v.w - bf2f(h3));
  reinterpret_cast<ushort4*>(hi)[i] = H;
  reinterpret_cast<ushort4*>(lo)[i] = L;
}

// ---------------------------------------------------------------------------
// Fused gather + split-GEMM layer:
//   v = 0.5*(Xhi+Xlo) + 0.5*relu( sum_s A_s @ W_s + bias )
// A gathered from X_hi/lo rows (r, r-delta, r+delta; OOB -> oob vector).
// 128x128 tile, 4 waves (2x2), BK=32, mfma_f32_16x16x32_bf16,
// 3-term split accumulation: hi*hi + hi*lo + lo*hi  (err ~1e-5/layer rel).
// m97-class structure: global_load_lds width-16 staging, 2 barriers/K-step.
// WRITE_MODE 0: write split bf16 pair (intermediate layer)
// WRITE_MODE 1: write fp32 (final layer -> d_out)
// ---------------------------------------------------------------------------
template <int WRITE_MODE>
__global__ __launch_bounds__(256, 3) void k_gemm(
    const u16* __restrict__ Xhi, const u16* __restrict__ Xlo,
    const u16* __restrict__ Whi, const u16* __restrict__ Wlo,
    const u16* __restrict__ oobhi, const u16* __restrict__ ooblo,
    const float* __restrict__ bias,
    float* __restrict__ outF, u16* __restrict__ outHi, u16* __restrict__ outLo,
    int delta) {
  __shared__ char smem[32768];
  char* const sAh = smem;
  char* const sAl = smem + 8192;
  char* const sBh = smem + 16384;
  char* const sBl = smem + 24576;

  const int tid  = threadIdx.x;
  const int w    = tid >> 6;
  const int lane = tid & 63;
  const int wm = w >> 1, wn = w & 1;       // wave -> 64x64 quadrant
  const int g4 = lane >> 4, i16 = lane & 15;
  const int bx = blockIdx.x, by = blockIdx.y;

  // Staging decomposition: LDS dest (wave-uniform) j*4096 + w*1024 + lane*16
  //   == kc*2048 + row*16  with kc = 2j + (w>>1), row = ((w&1)<<6)|lane.
  const int mst = ((w & 1) << 6) | lane;   // this thread's staged row
  const int kcw = w >> 1;                  // k-chunk parity for this wave

  const f32x4 zero = {0.f, 0.f, 0.f, 0.f};
  f32x4 acc[4][4];
#pragma unroll
  for (int a = 0; a < 4; ++a)
#pragma unroll
    for (int b = 0; b < 4; ++b) acc[a][b] = zero;

  const u16* bhRow = Whi + (size_t)(bx * 128 + mst) * K3;
  const u16* blRow = Wlo + (size_t)(bx * 128 + mst) * K3;

  // Fragment reads: tile[kc=g4][row][8 bf16] -> 16B contiguous per lane.
  // Bank audit: each 16-lane group covers all 32 banks 2x -> conflict-free.
  const int fragA = g4 * 2048 + wm * 1024 + i16 * 16;
  const int fragB = g4 * 2048 + wn * 1024 + i16 * 16;
  const int grow  = by * 128 + mst;

  for (int s = 0; s < 3; ++s) {
    const int sr = (s == 0) ? grow : ((s == 1) ? grow - delta : grow + delta);
    const bool valid = (sr >= 0) && (sr < NROWS);
    const u16* ahRow = valid ? (Xhi + (size_t)sr * DIM) : oobhi;
    const u16* alRow = valid ? (Xlo + (size_t)sr * DIM) : ooblo;
    const u16* bhSeg = bhRow + s * DIM;
    const u16* blSeg = blRow + s * DIM;

    for (int k0 = 0; k0 < DIM; k0 += 32) {
#pragma unroll
      for (int j = 0; j < 2; ++j) {
        const int ksrc = k0 + (2 * j + kcw) * 8;
        const int loff = j * 4096 + w * 1024;
        gload16(ahRow + ksrc, sAh + loff);
        gload16(alRow + ksrc, sAl + loff);
        gload16(bhSeg + ksrc, sBh + loff);
        gload16(blSeg + ksrc, sBl + loff);
      }
      __syncthreads();   // compiler drains vmcnt before barrier -> tiles ready

      bf16x8 bh[4], bl[4];
#pragma unroll
      for (int fn = 0; fn < 4; ++fn) {
        bh[fn] = *(const bf16x8*)(sBh + fragB + fn * 256);
        bl[fn] = *(const bf16x8*)(sBl + fragB + fn * 256);
      }
#pragma unroll
      for (int fm = 0; fm < 4; ++fm) {
        const bf16x8 ah = *(const bf16x8*)(sAh + fragA + fm * 256);
        const bf16x8 al = *(const bf16x8*)(sAl + fragA + fm * 256);
#pragma unroll
        for (int fn = 0; fn < 4; ++fn) {
          acc[fm][fn] = __builtin_amdgcn_mfma_f32_16x16x32_bf16(ah, bh[fn], acc[fm][fn], 0, 0, 0);
          acc[fm][fn] = __builtin_amdgcn_mfma_f32_16x16x32_bf16(ah, bl[fn], acc[fm][fn], 0, 0, 0);
          acc[fm][fn] = __builtin_amdgcn_mfma_f32_16x16x32_bf16(al, bh[fn], acc[fm][fn], 0, 0, 0);
        }
      }
      __syncthreads();   // protect LDS from next stage
    }
  }

  // epilogue: bias + relu + residual (reconstructed exactly from split pair)
  const int col0 = bx * 128 + wn * 64;
  const int row0 = by * 128 + wm * 64;
#pragma unroll
  for (int fn = 0; fn < 4; ++fn) {
    const int col = col0 + fn * 16 + i16;
    const float bv = bias[col];
#pragma unroll
    for (int fm = 0; fm < 4; ++fm) {
      const int rbase = row0 + fm * 16 + g4 * 4;
#pragma unroll
      for (int r = 0; r < 4; ++r) {
        const size_t off = (size_t)(rbase + r) * DIM + col;
        float v = acc[fm][fn][r] + bv;
        v = v > 0.f ? v : 0.f;
        const float res = bf2f(Xhi[off]) + bf2f(Xlo[off]);
        v = 0.5f * res + 0.5f * v;
        if (WRITE_MODE == 1) {
          outF[off] = v;
        } else {
          const u16 h = f2bf(v);
          outHi[off] = h;
          outLo[off] = f2bf(v - bf2f(h));
        }
      }
    }
  }
}

// ---------------------------------------------------------------------------
extern "C" void kernel_launch(void* const* d_in, const int* in_sizes, int n_in,
                              void* d_out, int out_size, void* d_ws, size_t ws_size,
                              hipStream_t stream) {
  const float* X   = (const float*)d_in[0];
  const float* Ws  = (const float*)d_in[1];
  const float* bs  = (const float*)d_in[2];
  const float* oob = (const float*)d_in[3];

  char* ws = (char*)d_ws;
  u16* WThi = (u16*)ws;  ws += (size_t)NLAYERS * DIM * K3 * 2;   // 25,165,824 B
  u16* WTlo = (u16*)ws;  ws += (size_t)NLAYERS * DIM * K3 * 2;
  u16* Xh[2]; u16* Xl[2];
  Xh[0] = (u16*)ws;  ws += (size_t)NROWS * DIM * 2;              // 16,777,216 B
  Xl[0] = (u16*)ws;  ws += (size_t)NROWS * DIM * 2;
  Xh[1] = (u16*)ws;  ws += (size_t)NROWS * DIM * 2;
  Xl[1] = (u16*)ws;  ws += (size_t)NROWS * DIM * 2;
  u16* Ohi = (u16*)ws;  ws += 2048;
  u16* Olo = (u16*)ws;  ws += 2048;
  // total ~117.5 MB of d_ws

  k_prep_w<<<dim3(K3 / 32, DIM / 32, NLAYERS), dim3(32, 8), 0, stream>>>(Ws, WThi, WTlo);
  k_oob<<<dim3(4), dim3(256), 0, stream>>>(oob, Ohi, Olo);
  k_split<<<dim3(NROWS * DIM / 4 / 256), dim3(256), 0, stream>>>(X, Xh[0], Xl[0]);

  const int deltas[NLAYERS] = {1, 2, 4, 1};
  int cur = 0;
  for (int i = 0; i < NLAYERS; ++i) {
    const u16* whi = WThi + (size_t)i * DIM * K3;
    const u16* wlo = WTlo + (size_t)i * DIM * K3;
    const float* bi = bs + (size_t)i * DIM;
    // grid: bx (8 col-panels) fastest -> xcd = linear%8 = bx, so each XCD's
    // L2 sees exactly one 3 MB B-panel (hi+lo) -> L2-resident weights.
    if (i < NLAYERS - 1) {
      k_gemm<0><<<dim3(DIM / 128, NROWS / 128), dim3(256), 0, stream>>>(
          Xh[cur], Xl[cur], whi, wlo, Ohi, Olo, bi,
          nullptr, Xh[cur ^ 1], Xl[cur ^ 1], deltas[i]);
    } else {
      k_gemm<1><<<dim3(DIM / 128, NROWS / 128), dim3(256), 0, stream>>>(
          Xh[cur], Xl[cur], whi, wlo, Ohi, Olo, bi,
          (float*)d_out, nullptr, nullptr, deltas[i]);
    }
    cur ^= 1;
  }
}

// Round 10
// 715.231 us; speedup vs baseline: 1.8498x; 1.8498x over previous
//
#include <hip/hip_runtime.h>

#define NROWS 8192
#define DIM   1024
#define K3    3072
#define NLAYERS 4

typedef unsigned short u16;
typedef __attribute__((ext_vector_type(8))) __bf16 bf16x8;
typedef __attribute__((ext_vector_type(8))) unsigned short u16x8;
typedef __attribute__((ext_vector_type(4))) float  f32x4;

__device__ __forceinline__ u16 f2bf(float f) {
  unsigned u = __builtin_bit_cast(unsigned, f);
  u += 0x7FFFu + ((u >> 16) & 1u);   // round-to-nearest-even to bf16
  return (u16)(u >> 16);
}
__device__ __forceinline__ float bf2f(u16 h) {
  unsigned u = ((unsigned)h) << 16;
  return __builtin_bit_cast(float, u);
}

__device__ __forceinline__ void gload16(const void* g, void* l) {
  __builtin_amdgcn_global_load_lds((__attribute__((address_space(1))) void*)g,
                                   (__attribute__((address_space(3))) void*)l,
                                   16, 0, 0);
}

// Blocked (k-chunk-major) layouts, kc = k>>3:
//   X  : [128 kc][8192 row][8]   elem (row,k) at kc*NROWS*8 + row*8 + (k&7)
//   WT : [384 kc][1024 col][8]   elem (col,kk) at kc*DIM*8 + col*8 + (kk&7)
//   oob: linear [1024] (== [128 kc][8])
// Staging loads become lane-contiguous: 64 lanes x 16B = 1KB per instr.

// ---------------------------------------------------------------------------
// W [L][3072][1024] f32 -> WT_hi/lo blocked bf16 split. Elementwise reindex.
// ---------------------------------------------------------------------------
__global__ void k_prep_w(const float* __restrict__ Ws,
                         u16* __restrict__ WThi, u16* __restrict__ WTlo) {
  const int L   = blockIdx.y;
  const int idx = blockIdx.x * 256 + threadIdx.x;   // 0 .. K3*DIM-1
  const int k = idx >> 10;            // row of W = contraction index
  const int n = idx & 1023;           // col of W = output col
  const float v = Ws[(size_t)L * K3 * DIM + idx];   // coalesced (n fastest)
  const u16 h = f2bf(v);
  const size_t dst = (size_t)L * K3 * DIM + (size_t)(k >> 3) * (DIM * 8)
                   + (size_t)n * 8 + (k & 7);
  WThi[dst] = h;
  WTlo[dst] = f2bf(v - bf2f(h));
}

__global__ void k_oob(const float* __restrict__ oob, u16* __restrict__ hi,
                      u16* __restrict__ lo) {
  const int i = blockIdx.x * 256 + threadIdx.x;
  if (i < DIM) {
    const float v = oob[i];
    const u16 h = f2bf(v);
    hi[i] = h;
    lo[i] = f2bf(v - bf2f(h));
  }
}

// X f32 [8192][1024] -> blocked split pair. One thread = one (row, kc):
// reads 32B of one row, writes 16B hi + 16B lo (writes coalesced over row).
__global__ void k_split(const float* __restrict__ X, u16* __restrict__ hi,
                        u16* __restrict__ lo) {
  const int idx = blockIdx.x * 256 + threadIdx.x;   // 0 .. NROWS*128-1
  const int r = idx & (NROWS - 1);
  const int c = idx >> 13;                          // kc 0..127
  const float4 v0 = *reinterpret_cast<const float4*>(X + (size_t)r * DIM + c * 8);
  const float4 v1 = *reinterpret_cast<const float4*>(X + (size_t)r * DIM + c * 8 + 4);
  const float f[8] = {v0.x, v0.y, v0.z, v0.w, v1.x, v1.y, v1.z, v1.w};
  u16x8 H, Lv;
#pragma unroll
  for (int e = 0; e < 8; ++e) {
    const u16 h = f2bf(f[e]);
    H[e]  = h;
    Lv[e] = f2bf(f[e] - bf2f(h));
  }
  const size_t dst = (size_t)c * (NROWS * 8) + (size_t)r * 8;
  *reinterpret_cast<u16x8*>(hi + dst) = H;
  *reinterpret_cast<u16x8*>(lo + dst) = Lv;
}

// ---------------------------------------------------------------------------
// Fused gather + split-GEMM layer (m97-class 128x128, BK=32, 16x16x32 bf16,
// 3-term split: hi*hi + hi*lo + lo*hi). Inputs/outputs in blocked layout.
// WRITE_MODE 0: blocked split pair out; WRITE_MODE 1: row-major fp32 d_out.
// ---------------------------------------------------------------------------
template <int WRITE_MODE>
__global__ __launch_bounds__(256, 3) void k_gemm(
    const u16* __restrict__ Xhi, const u16* __restrict__ Xlo,
    const u16* __restrict__ Whi, const u16* __restrict__ Wlo,
    const u16* __restrict__ oobhi, const u16* __restrict__ ooblo,
    const float* __restrict__ bias,
    float* __restrict__ outF, u16* __restrict__ outHi, u16* __restrict__ outLo,
    int delta) {
  __shared__ char smem[32768];
  char* const sAh = smem;
  char* const sAl = smem + 8192;
  char* const sBh = smem + 16384;
  char* const sBl = smem + 24576;

  const int tid  = threadIdx.x;
  const int w    = tid >> 6;
  const int lane = tid & 63;
  const int wm = w >> 1, wn = w & 1;       // wave -> 64x64 quadrant
  const int g4 = lane >> 4, i16 = lane & 15;
  const int bx = blockIdx.x, by = blockIdx.y;

  // LDS dest (wave-uniform) j*4096 + w*1024 + lane*16
  //   == kc*2048 + row*16 with kc = 2j + (w>>1), row = ((w&1)<<6)|lane.
  const int mst = ((w & 1) << 6) | lane;   // this thread's staged row/col
  const int kcw = w >> 1;

  const f32x4 zero = {0.f, 0.f, 0.f, 0.f};
  f32x4 acc[4][4];
#pragma unroll
  for (int a = 0; a < 4; ++a)
#pragma unroll
    for (int b = 0; b < 4; ++b) acc[a][b] = zero;

  const int bcol = bx * 128 + mst;          // staged output col (B)
  const int grow = by * 128 + mst;          // staged output row (A)

  // Fragment reads: tile[kc=g4][row][8 bf16] -> 16B contiguous per lane.
  const int fragA = g4 * 2048 + wm * 1024 + i16 * 16;
  const int fragB = g4 * 2048 + wn * 1024 + i16 * 16;

  for (int s = 0; s < 3; ++s) {
    const int sr = (s == 0) ? grow : ((s == 1) ? grow - delta : grow + delta);
    const bool valid = (sr >= 0) && (sr < NROWS);

    for (int k0 = 0; k0 < DIM; k0 += 32) {
#pragma unroll
      for (int j = 0; j < 2; ++j) {
        const int ksrc = k0 + (2 * j + kcw) * 8;       // k within segment
        const int kk   = s * DIM + ksrc;               // k within K3
        const int loff = j * 4096 + w * 1024;
        // A: lane-contiguous 16B at [ksrc>>3][sr]; OOB lanes -> oob vector
        const size_t aoff = (size_t)(ksrc >> 3) * (NROWS * 8) + (size_t)sr * 8;
        const u16* ah = valid ? (Xhi + aoff) : (oobhi + ksrc);
        const u16* al = valid ? (Xlo + aoff) : (ooblo + ksrc);
        gload16(ah, sAh + loff);
        gload16(al, sAl + loff);
        // B: lane-contiguous 16B at [kk>>3][bcol]
        const size_t boff = (size_t)(kk >> 3) * (DIM * 8) + (size_t)bcol * 8;
        gload16(Whi + boff, sBh + loff);
        gload16(Wlo + boff, sBl + loff);
      }
      __syncthreads();   // vmcnt drained before barrier -> tiles ready

      bf16x8 bh[4], bl[4];
#pragma unroll
      for (int fn = 0; fn < 4; ++fn) {
        bh[fn] = *(const bf16x8*)(sBh + fragB + fn * 256);
        bl[fn] = *(const bf16x8*)(sBl + fragB + fn * 256);
      }
#pragma unroll
      for (int fm = 0; fm < 4; ++fm) {
        const bf16x8 ah = *(const bf16x8*)(sAh + fragA + fm * 256);
        const bf16x8 al = *(const bf16x8*)(sAl + fragA + fm * 256);
#pragma unroll
        for (int fn = 0; fn < 4; ++fn) {
          acc[fm][fn] = __builtin_amdgcn_mfma_f32_16x16x32_bf16(ah, bh[fn], acc[fm][fn], 0, 0, 0);
          acc[fm][fn] = __builtin_amdgcn_mfma_f32_16x16x32_bf16(ah, bl[fn], acc[fm][fn], 0, 0, 0);
          acc[fm][fn] = __builtin_amdgcn_mfma_f32_16x16x32_bf16(al, bh[fn], acc[fm][fn], 0, 0, 0);
        }
      }
      __syncthreads();   // protect LDS from next stage
    }
  }

  // epilogue: bias + relu + residual (exact reconstruct from split pair)
  const int col0 = bx * 128 + wn * 64;
  const int row0 = by * 128 + wm * 64;
#pragma unroll
  for (int fn = 0; fn < 4; ++fn) {
    const int col = col0 + fn * 16 + i16;
    const float bv = bias[col];
    const size_t cb = (size_t)(col >> 3) * (NROWS * 8) + (col & 7);  // blocked col base
#pragma unroll
    for (int fm = 0; fm < 4; ++fm) {
      const int rbase = row0 + fm * 16 + g4 * 4;
#pragma unroll
      for (int r = 0; r < 4; ++r) {
        const int row = rbase + r;
        const size_t offB = cb + (size_t)row * 8;       // blocked offset
        float v = acc[fm][fn][r] + bv;
        v = v > 0.f ? v : 0.f;
        const float res = bf2f(Xhi[offB]) + bf2f(Xlo[offB]);
        v = 0.5f * res + 0.5f * v;
        if (WRITE_MODE == 1) {
          outF[(size_t)row * DIM + col] = v;            // row-major fp32
        } else {
          const u16 h = f2bf(v);
          outHi[offB] = h;
          outLo[offB] = f2bf(v - bf2f(h));
        }
      }
    }
  }
}

// ---------------------------------------------------------------------------
extern "C" void kernel_launch(void* const* d_in, const int* in_sizes, int n_in,
                              void* d_out, int out_size, void* d_ws, size_t ws_size,
                              hipStream_t stream) {
  const float* X   = (const float*)d_in[0];
  const float* Ws  = (const float*)d_in[1];
  const float* bs  = (const float*)d_in[2];
  const float* oob = (const float*)d_in[3];

  char* ws = (char*)d_ws;
  u16* WThi = (u16*)ws;  ws += (size_t)NLAYERS * DIM * K3 * 2;   // 25,165,824 B
  u16* WTlo = (u16*)ws;  ws += (size_t)NLAYERS * DIM * K3 * 2;
  u16* Xh[2]; u16* Xl[2];
  Xh[0] = (u16*)ws;  ws += (size_t)NROWS * DIM * 2;              // 16,777,216 B
  Xl[0] = (u16*)ws;  ws += (size_t)NROWS * DIM * 2;
  Xh[1] = (u16*)ws;  ws += (size_t)NROWS * DIM * 2;
  Xl[1] = (u16*)ws;  ws += (size_t)NROWS * DIM * 2;
  u16* Ohi = (u16*)ws;  ws += 2048;
  u16* Olo = (u16*)ws;  ws += 2048;
  // total ~117.5 MB of d_ws

  k_prep_w<<<dim3(K3 * DIM / 256, NLAYERS), dim3(256), 0, stream>>>(Ws, WThi, WTlo);
  k_oob<<<dim3(4), dim3(256), 0, stream>>>(oob, Ohi, Olo);
  k_split<<<dim3(NROWS * (DIM / 8) / 256), dim3(256), 0, stream>>>(X, Xh[0], Xl[0]);

  const int deltas[NLAYERS] = {1, 2, 4, 1};
  int cur = 0;
  for (int i = 0; i < NLAYERS; ++i) {
    const u16* whi = WThi + (size_t)i * DIM * K3;
    const u16* wlo = WTlo + (size_t)i * DIM * K3;
    const float* bi = bs + (size_t)i * DIM;
    if (i < NLAYERS - 1) {
      k_gemm<0><<<dim3(DIM / 128, NROWS / 128), dim3(256), 0, stream>>>(
          Xh[cur], Xl[cur], whi, wlo, Ohi, Olo, bi,
          nullptr, Xh[cur ^ 1], Xl[cur ^ 1], deltas[i]);
    } else {
      k_gemm<1><<<dim3(DIM / 128, NROWS / 128), dim3(256), 0, stream>>>(
          Xh[cur], Xl[cur], whi, wlo, Ohi, Olo, bi,
          (float*)d_out, nullptr, nullptr, deltas[i]);
    }
    cur ^= 1;
  }
}

// Round 11
// 630.412 us; speedup vs baseline: 2.0987x; 1.1345x over previous
//
#include <hip/hip_runtime.h>

#define NROWS 8192
#define DIM   1024
#define K3    3072
#define NLAYERS 4

typedef unsigned short u16;
typedef __attribute__((ext_vector_type(8))) __bf16 bf16x8;
typedef __attribute__((ext_vector_type(8))) unsigned short u16x8;
typedef __attribute__((ext_vector_type(4))) float  f32x4;

__device__ __forceinline__ u16 f2bf(float f) {
  unsigned u = __builtin_bit_cast(unsigned, f);
  u += 0x7FFFu + ((u >> 16) & 1u);   // round-to-nearest-even to bf16
  return (u16)(u >> 16);
}
__device__ __forceinline__ float bf2f(u16 h) {
  unsigned u = ((unsigned)h) << 16;
  return __builtin_bit_cast(float, u);
}

__device__ __forceinline__ void gload16(const void* g, void* l) {
  __builtin_amdgcn_global_load_lds((__attribute__((address_space(1))) void*)g,
                                   (__attribute__((address_space(3))) void*)l,
                                   16, 0, 0);
}

// Blocked (k-chunk-major) layouts, kc = k>>3:
//   X  : [128 kc][8192 row][8]   elem (row,k) at kc*NROWS*8 + row*8 + (k&7)
//   WT : [384 kc][1024 col][8]   elem (col,kk) at kc*DIM*8 + col*8 + (kk&7)
//   oob: linear [1024] (== [128 kc][8])

// ---------------------------------------------------------------------------
// W [L][3072][1024] f32 -> WT_hi/lo blocked bf16 split.
// Thread per (kc, n): 8 coalesced 256B reads, one coalesced u16x8 write each.
// ---------------------------------------------------------------------------
__global__ void k_prep_w(const float* __restrict__ Ws,
                         u16* __restrict__ WThi, u16* __restrict__ WTlo) {
  const int L   = blockIdx.y;
  const int idx = blockIdx.x * 256 + threadIdx.x;   // 0 .. K3/8*DIM-1
  const int kc = idx >> 10;           // k-chunk 0..383
  const int n  = idx & 1023;          // output col (lane-consecutive)
  const size_t src = (size_t)L * K3 * DIM + (size_t)kc * 8 * DIM + n;
  u16x8 H, Lv;
#pragma unroll
  for (int e = 0; e < 8; ++e) {
    const float v = Ws[src + (size_t)e * DIM];      // 64 lanes x 4B contiguous
    const u16 h = f2bf(v);
    H[e]  = h;
    Lv[e] = f2bf(v - bf2f(h));
  }
  const size_t dst = (size_t)L * K3 * DIM + (size_t)kc * (DIM * 8) + (size_t)n * 8;
  *reinterpret_cast<u16x8*>(WThi + dst) = H;        // 64 lanes x 16B contiguous
  *reinterpret_cast<u16x8*>(WTlo + dst) = Lv;
}

__global__ void k_oob(const float* __restrict__ oob, u16* __restrict__ hi,
                      u16* __restrict__ lo) {
  const int i = blockIdx.x * 256 + threadIdx.x;
  if (i < DIM) {
    const float v = oob[i];
    const u16 h = f2bf(v);
    hi[i] = h;
    lo[i] = f2bf(v - bf2f(h));
  }
}

// X f32 [8192][1024] -> blocked split pair (writes coalesced over row).
__global__ void k_split(const float* __restrict__ X, u16* __restrict__ hi,
                        u16* __restrict__ lo) {
  const int idx = blockIdx.x * 256 + threadIdx.x;   // 0 .. NROWS*128-1
  const int r = idx & (NROWS - 1);
  const int c = idx >> 13;                          // kc 0..127
  const float4 v0 = *reinterpret_cast<const float4*>(X + (size_t)r * DIM + c * 8);
  const float4 v1 = *reinterpret_cast<const float4*>(X + (size_t)r * DIM + c * 8 + 4);
  const float f[8] = {v0.x, v0.y, v0.z, v0.w, v1.x, v1.y, v1.z, v1.w};
  u16x8 H, Lv;
#pragma unroll
  for (int e = 0; e < 8; ++e) {
    const u16 h = f2bf(f[e]);
    H[e]  = h;
    Lv[e] = f2bf(f[e] - bf2f(h));
  }
  const size_t dst = (size_t)c * (NROWS * 8) + (size_t)r * 8;
  *reinterpret_cast<u16x8*>(hi + dst) = H;
  *reinterpret_cast<u16x8*>(lo + dst) = Lv;
}

// ---------------------------------------------------------------------------
// Fused gather + split-GEMM layer, 2-phase double-buffered:
//   per K-step: STAGE(t+1 -> buf^1) ; COMPUTE(buf) ; one barrier.
// 128x128 tile, 4 waves, BK=32, 16x16x32 bf16, 3-term split.
// XCD row-band swizzle: xcd gets an 8-block by-band (X slice L2-resident).
// ---------------------------------------------------------------------------
template <int WRITE_MODE>
__global__ __launch_bounds__(256, 2) void k_gemm(
    const u16* __restrict__ Xhi, const u16* __restrict__ Xlo,
    const u16* __restrict__ Whi, const u16* __restrict__ Wlo,
    const u16* __restrict__ oobhi, const u16* __restrict__ ooblo,
    const float* __restrict__ bias,
    float* __restrict__ outF, u16* __restrict__ outHi, u16* __restrict__ outLo,
    int delta) {
  __shared__ char smem[65536];   // 2 buffers x [Ah 8K][Al 8K][Bh 8K][Bl 8K]

  const int tid  = threadIdx.x;
  const int w    = tid >> 6;
  const int lane = tid & 63;
  const int wm = w >> 1, wn = w & 1;
  const int g4 = lane >> 4, i16 = lane & 15;

  // XCD row-band swizzle (bijective): linear L (x fastest) -> xcd = L&7 owns
  // by in [8*xcd, 8*xcd+8) for all bx -> per-XCD X slice 4.2MB, W k-slice
  // shared by 8 co-resident bx-blocks.
  const int Lr  = blockIdx.y * 8 + blockIdx.x;
  const int xcd = Lr & 7, ii = Lr >> 3;
  const int bx  = ii & 7;
  const int by  = (xcd << 3) | (ii >> 3);

  const int mst = ((w & 1) << 6) | lane;   // staged row/col (kc=2j+(w>>1))
  const int kcw = w >> 1;

  const f32x4 zero = {0.f, 0.f, 0.f, 0.f};
  f32x4 acc[4][4];
#pragma unroll
  for (int a = 0; a < 4; ++a)
#pragma unroll
    for (int b = 0; b < 4; ++b) acc[a][b] = zero;

  const int bcol = bx * 128 + mst;
  const int grow = by * 128 + mst;

  const int fragA = g4 * 2048 + wm * 1024 + i16 * 16;
  const int fragB = g4 * 2048 + wn * 1024 + i16 * 16;

  // t in [0,96): s = t>>5 (segment), k0 = (t&31)*32
  auto STAGE = [&](int t, int bo) {
    const int s  = t >> 5;
    const int k0 = (t & 31) << 5;
    const int sr = (s == 0) ? grow : ((s == 1) ? grow - delta : grow + delta);
    const bool valid = (sr >= 0) && (sr < NROWS);
#pragma unroll
    for (int j = 0; j < 2; ++j) {
      const int ksrc = k0 + (2 * j + kcw) * 8;
      const int kk   = s * DIM + ksrc;
      const int loff = bo + j * 4096 + w * 1024;
      const size_t aoff = (size_t)(ksrc >> 3) * (NROWS * 8) + (size_t)sr * 8;
      gload16(valid ? (Xhi + aoff) : (oobhi + ksrc), smem + loff);
      gload16(valid ? (Xlo + aoff) : (ooblo + ksrc), smem + 8192 + loff);
      const size_t boff = (size_t)(kk >> 3) * (DIM * 8) + (size_t)bcol * 8;
      gload16(Whi + boff, smem + 16384 + loff);
      gload16(Wlo + boff, smem + 24576 + loff);
    }
  };

  auto COMPUTE = [&](int bo) {
    bf16x8 bh[4], bl[4];
#pragma unroll
    for (int fn = 0; fn < 4; ++fn) {
      bh[fn] = *(const bf16x8*)(smem + 16384 + bo + fragB + fn * 256);
      bl[fn] = *(const bf16x8*)(smem + 24576 + bo + fragB + fn * 256);
    }
#pragma unroll
    for (int fm = 0; fm < 4; ++fm) {
      const bf16x8 ah = *(const bf16x8*)(smem + bo + fragA + fm * 256);
      const bf16x8 al = *(const bf16x8*)(smem + 8192 + bo + fragA + fm * 256);
#pragma unroll
      for (int fn = 0; fn < 4; ++fn) {
        acc[fm][fn] = __builtin_amdgcn_mfma_f32_16x16x32_bf16(ah, bh[fn], acc[fm][fn], 0, 0, 0);
        acc[fm][fn] = __builtin_amdgcn_mfma_f32_16x16x32_bf16(ah, bl[fn], acc[fm][fn], 0, 0, 0);
        acc[fm][fn] = __builtin_amdgcn_mfma_f32_16x16x32_bf16(al, bh[fn], acc[fm][fn], 0, 0, 0);
      }
    }
  };

  STAGE(0, 0);
  __syncthreads();            // prologue drain
  int bo = 0;
#pragma unroll 1
  for (int t = 0; t < 95; ++t) {
    STAGE(t + 1, bo ^ 32768); // loads fly under this step's MFMA
    COMPUTE(bo);
    __syncthreads();          // single barrier: drains vmcnt+lgkmcnt
    bo ^= 32768;
  }
  COMPUTE(bo);                // last step, no prefetch

  // epilogue: bias + relu + residual (exact reconstruct from split pair)
  const int col0 = bx * 128 + wn * 64;
  const int row0 = by * 128 + wm * 64;
#pragma unroll
  for (int fn = 0; fn < 4; ++fn) {
    const int col = col0 + fn * 16 + i16;
    const float bv = bias[col];
    const size_t cb = (size_t)(col >> 3) * (NROWS * 8) + (col & 7);
#pragma unroll
    for (int fm = 0; fm < 4; ++fm) {
      const int rbase = row0 + fm * 16 + g4 * 4;
#pragma unroll
      for (int r = 0; r < 4; ++r) {
        const int row = rbase + r;
        const size_t offB = cb + (size_t)row * 8;
        float v = acc[fm][fn][r] + bv;
        v = v > 0.f ? v : 0.f;
        const float res = bf2f(Xhi[offB]) + bf2f(Xlo[offB]);
        v = 0.5f * res + 0.5f * v;
        if (WRITE_MODE == 1) {
          outF[(size_t)row * DIM + col] = v;
        } else {
          const u16 h = f2bf(v);
          outHi[offB] = h;
          outLo[offB] = f2bf(v - bf2f(h));
        }
      }
    }
  }
}

// ---------------------------------------------------------------------------
extern "C" void kernel_launch(void* const* d_in, const int* in_sizes, int n_in,
                              void* d_out, int out_size, void* d_ws, size_t ws_size,
                              hipStream_t stream) {
  const float* X   = (const float*)d_in[0];
  const float* Ws  = (const float*)d_in[1];
  const float* bs  = (const float*)d_in[2];
  const float* oob = (const float*)d_in[3];

  char* ws = (char*)d_ws;
  u16* WThi = (u16*)ws;  ws += (size_t)NLAYERS * DIM * K3 * 2;   // 25,165,824 B
  u16* WTlo = (u16*)ws;  ws += (size_t)NLAYERS * DIM * K3 * 2;
  u16* Xh[2]; u16* Xl[2];
  Xh[0] = (u16*)ws;  ws += (size_t)NROWS * DIM * 2;              // 16,777,216 B
  Xl[0] = (u16*)ws;  ws += (size_t)NROWS * DIM * 2;
  Xh[1] = (u16*)ws;  ws += (size_t)NROWS * DIM * 2;
  Xl[1] = (u16*)ws;  ws += (size_t)NROWS * DIM * 2;
  u16* Ohi = (u16*)ws;  ws += 2048;
  u16* Olo = (u16*)ws;  ws += 2048;
  // total ~117.5 MB of d_ws

  k_prep_w<<<dim3(K3 * DIM / 8 / 256, NLAYERS), dim3(256), 0, stream>>>(Ws, WThi, WTlo);
  k_oob<<<dim3(4), dim3(256), 0, stream>>>(oob, Ohi, Olo);
  k_split<<<dim3(NROWS * (DIM / 8) / 256), dim3(256), 0, stream>>>(X, Xh[0], Xl[0]);

  const int deltas[NLAYERS] = {1, 2, 4, 1};
  int cur = 0;
  for (int i = 0; i < NLAYERS; ++i) {
    const u16* whi = WThi + (size_t)i * DIM * K3;
    const u16* wlo = WTlo + (size_t)i * DIM * K3;
    const float* bi = bs + (size_t)i * DIM;
    if (i < NLAYERS - 1) {
      k_gemm<0><<<dim3(DIM / 128, NROWS / 128), dim3(256), 0, stream>>>(
          Xh[cur], Xl[cur], whi, wlo, Ohi, Olo, bi,
          nullptr, Xh[cur ^ 1], Xl[cur ^ 1], deltas[i]);
    } else {
      k_gemm<1><<<dim3(DIM / 128, NROWS / 128), dim3(256), 0, stream>>>(
          Xh[cur], Xl[cur], whi, wlo, Ohi, Olo, bi,
          (float*)d_out, nullptr, nullptr, deltas[i]);
    }
    cur ^= 1;
  }
}